// Round 15
// baseline (242.951 us; speedup 1.0000x reference)
//
#include <hip/hip_runtime.h>
#include <hip/hip_bf16.h>
#include <math.h>

#define T_TOK 4096
#define DIM   1024
#define HDIM  256
#define N_SH  2
#define N_RT  32
#define N_E   34
#define TOPK  4
#define TB    128
#define MAXPB 200
#define NSLOT 6
#define OSW   34          // ostage row stride (32 cols + 2 pad)
#define PACKB (2 * N_E * 128)   // 8704 pack blocks
#define PREB  (PACKB + T_TOK/4) // merged grid

typedef short bf16x8 __attribute__((ext_vector_type(8)));
typedef float f32x4  __attribute__((ext_vector_type(4)));
typedef unsigned short u16x8 __attribute__((ext_vector_type(8)));

__device__ __forceinline__ ushort f2b(float v) {
    __hip_bfloat16 h = __float2bfloat16(v);
    return *reinterpret_cast<const ushort*>(&h);
}
__device__ __forceinline__ float b2f(ushort u) {
    unsigned int x = ((unsigned int)u) << 16;
    return __uint_as_float(x);
}
__device__ __forceinline__ float gelu_tanh(float x) {
    float z = 0.7978845608028654f * (x + 0.044715f * x * x * x);
    float e = __expf(2.0f * z);
    float t = 1.0f - 2.0f / (e + 1.0f);
    return 0.5f * x * (1.0f + t);
}

// ---------------- merged: weight pack + RMSNorm/router (interleaved blocks) ----------
// bi in [0,8192): (bi&7)==0 -> router block bi>>3; else pack block.
// bi in [8192,PREB): pack blocks. 1 router block per 8 overlaps the two phases.
__global__ __launch_bounds__(256) void fused_pre(
    const float* __restrict__ x, const float* __restrict__ rms_w,
    const float* __restrict__ cent,
    const float* __restrict__ sW1, const float* __restrict__ rW1,
    const float* __restrict__ sW2, const float* __restrict__ rW2,
    ushort* __restrict__ W1p, ushort* __restrict__ W2p,
    ushort* __restrict__ xnb, float* __restrict__ aff_out,
    int* __restrict__ tk_e, float* __restrict__ sscore)
{
    const int bi  = blockIdx.x;
    const int tid = threadIdx.x;

    __shared__ float xsh[4][DIM];        // router only (16 KB)
    __shared__ float logits[4][N_RT];

    const bool is_router = (bi < 8192) && ((bi & 7) == 0);

    if (!is_router) {
        // ---- pack branch ----
        const int pid = (bi < 8192) ? (bi - (bi >> 3) - 1) : (bi - T_TOK/4);
        const int z   = pid / (N_E * 128);          // 0: W1, 1: W2
        const int rem = pid - z * (N_E * 128);
        const int e   = rem >> 7;
        const int xb  = rem & 127;
        const int K = z ? HDIM : DIM;
        const int N = z ? DIM : HDIM;
        const float* srcS = z ? sW2 : sW1;
        const float* srcR = z ? rW2 : rW1;
        ushort* dst       = z ? W2p : W1p;
        const float* src = (e < N_SH) ? (srcS + (size_t)e * K * N)
                                      : (srcR + (size_t)(e - N_SH) * K * N);
        const int tile = xb * 4 + (tid >> 6);
        const int lane = tid & 63;
        const int l16 = lane & 15, lk = lane >> 4;
        const int kt  = K >> 5;
        const int n16 = tile / kt, k32 = tile % kt;
        const int n  = n16 * 16 + l16;
        const int kb = k32 * 32 + lk * 8;
        const float* s = src + (size_t)kb * N + n;
        u16x8 o;
        #pragma unroll
        for (int j = 0; j < 8; ++j) o[j] = f2b(s[(size_t)j * N]);
        *(u16x8*)(dst + (size_t)e * K * N + (size_t)tile * 512 + lane * 8) = o;
        return;
    }

    // ---- router branch: 4 tokens per block ----
    const int t0  = (bi >> 3) * 4;
    const int wid = tid >> 6;
    const int lane = tid & 63;
    const int t = t0 + wid;

    float4 xv[4], wv[4];
    float ss = 0.f;
    #pragma unroll
    for (int q = 0; q < 4; ++q) {
        xv[q] = ((const float4*)(x + (size_t)t * DIM))[lane + 64 * q];
        ss += xv[q].x*xv[q].x + xv[q].y*xv[q].y + xv[q].z*xv[q].z + xv[q].w*xv[q].w;
    }
    #pragma unroll
    for (int o = 32; o > 0; o >>= 1) ss += __shfl_down(ss, o);
    const float rstd = rsqrtf(__shfl(ss, 0) * (1.0f / (float)DIM) + 1e-6f);

    #pragma unroll
    for (int q = 0; q < 4; ++q)
        wv[q] = ((const float4*)rms_w)[lane + 64 * q];

    #pragma unroll
    for (int q = 0; q < 4; ++q) {
        float4 nv;
        nv.x = xv[q].x * rstd * wv[q].x;
        nv.y = xv[q].y * rstd * wv[q].y;
        nv.z = xv[q].z * rstd * wv[q].z;
        nv.w = xv[q].w * rstd * wv[q].w;
        ushort4 xb = make_ushort4(f2b(nv.x), f2b(nv.y), f2b(nv.z), f2b(nv.w));
        ((ushort4*)(xnb + (size_t)t * DIM))[lane + 64 * q] = xb;
        ((float4*)xsh[wid])[lane + 64 * q] = nv;
    }
    __syncthreads();

    #pragma unroll
    for (int ei = 0; ei < 8; ++ei) {
        const int e = wid * 8 + ei;
        const float4* c4 = (const float4*)(cent + (size_t)e * DIM);
        float a0 = 0.f, a1 = 0.f, a2 = 0.f, a3 = 0.f;
        #pragma unroll
        for (int q = 0; q < 4; ++q) {
            const float4 cv = c4[lane + 64 * q];
            const float4 x0 = ((const float4*)xsh[0])[lane + 64 * q];
            const float4 x1 = ((const float4*)xsh[1])[lane + 64 * q];
            const float4 x2 = ((const float4*)xsh[2])[lane + 64 * q];
            const float4 x3 = ((const float4*)xsh[3])[lane + 64 * q];
            a0 += cv.x*x0.x + cv.y*x0.y + cv.z*x0.z + cv.w*x0.w;
            a1 += cv.x*x1.x + cv.y*x1.y + cv.z*x1.z + cv.w*x1.w;
            a2 += cv.x*x2.x + cv.y*x2.y + cv.z*x2.z + cv.w*x2.w;
            a3 += cv.x*x3.x + cv.y*x3.y + cv.z*x3.z + cv.w*x3.w;
        }
        #pragma unroll
        for (int o = 32; o > 0; o >>= 1) {
            a0 += __shfl_down(a0, o);
            a1 += __shfl_down(a1, o);
            a2 += __shfl_down(a2, o);
            a3 += __shfl_down(a3, o);
        }
        if (lane == 0) {
            logits[0][e] = a0; logits[1][e] = a1;
            logits[2][e] = a2; logits[3][e] = a3;
        }
    }
    __syncthreads();

    {
        float v = (lane < N_RT) ? logits[wid][lane] : -INFINITY;
        float m = v;
        #pragma unroll
        for (int o = 32; o > 0; o >>= 1) m = fmaxf(m, __shfl_xor(m, o));
        float p = (lane < N_RT) ? expf(v - m) : 0.f;
        float s = p;
        #pragma unroll
        for (int o = 32; o > 0; o >>= 1) s += __shfl_xor(s, o);
        const float a = p / s;
        if (lane < N_RT) aff_out[(size_t)t * N_RT + lane] = a;
        if (lane < N_SH) sscore[(size_t)t * NSLOT + lane] = 1.f;

        float vv = (lane < N_RT) ? a : -1.f;
        #pragma unroll
        for (int it = 0; it < TOPK; ++it) {
            float mx = vv;
            #pragma unroll
            for (int o = 32; o > 0; o >>= 1) mx = fmaxf(mx, __shfl_xor(mx, o));
            unsigned long long msk = __ballot(vv == mx);
            int sel = __ffsll((long long)msk) - 1;
            sel = (sel < 0) ? 0 : (sel & (N_RT - 1));
            if (lane == 0) {
                tk_e[(size_t)t * TOPK + it] = sel;
                sscore[(size_t)t * NSLOT + 2 + it] = mx;
            }
            if (lane == sel) vv = -1.f;
        }
    }
}

// ---- scatter: block e compacts (token,slot) entries where tk_e == e ----
__global__ __launch_bounds__(64) void scatter_kernel(
    const int* __restrict__ tk_e, int* __restrict__ counts, int* __restrict__ lists)
{
    const int e    = blockIdx.x;
    const int lane = threadIdx.x;
    const unsigned long long lt = (1ull << lane) - 1ull;
    int base = 0;
    int* lst = lists + (size_t)e * T_TOK;
    for (int c = 0; c < T_TOK * TOPK; c += 256) {
        const int4 v = *(const int4*)(tk_e + c + lane * 4);
        const bool p0 = (v.x == e), p1 = (v.y == e), p2 = (v.z == e), p3 = (v.w == e);
        const unsigned long long m0 = __ballot(p0);
        const unsigned long long m1 = __ballot(p1);
        const unsigned long long m2 = __ballot(p2);
        const unsigned long long m3 = __ballot(p3);
        const int c0 = __popcll(m0), c1 = __popcll(m1), c2 = __popcll(m2);
        if (p0) lst[base + __popcll(m0 & lt)] = c + lane * 4 + 0;
        if (p1) lst[base + c0 + __popcll(m1 & lt)] = c + lane * 4 + 1;
        if (p2) lst[base + c0 + c1 + __popcll(m2 & lt)] = c + lane * 4 + 2;
        if (p3) lst[base + c0 + c1 + c2 + __popcll(m3 & lt)] = c + lane * 4 + 3;
        base += c0 + c1 + c2 + __popcll(m3);
    }
    if (lane == 0) counts[e] = base;
}

// ---- residual init (fallback path only): y = bf16(xn) ----
__global__ __launch_bounds__(256) void residual_init(
    const ushort* __restrict__ xnb, float* __restrict__ y)
{
    const int idx = blockIdx.x * 256 + threadIdx.x;
    const ushort4 xr = *(const ushort4*)(xnb + (size_t)idx * 4);
    float4 a;
    a.x = b2f(xr.x); a.y = b2f(xr.y); a.z = b2f(xr.z); a.w = b2f(xr.w);
    ((float4*)y)[idx] = a;
}

// ---------------- fused 2-layer expert MLP (r13-verified structure) ----------------
// Phase 1 (K=1024): wave (mq=w>>1, nh=w&1): M=32, N=128, 16 MFMA/step.
// Phase 2 (K=256): wave (mh=w>>2, nq=w&3): M=64, N=64, 16 MFMA/step, 4 jc chunks.
// Routed blocks derive (expert, tile) from counts directly (no items buffer).
template<bool ATOMIC>
__global__ __launch_bounds__(512, 2) void moe_mfma(
    const ushort* __restrict__ xnb,
    const ushort* __restrict__ W1p, const ushort* __restrict__ W2p,
    const float* __restrict__ sb1, const float* __restrict__ sb2,
    const float* __restrict__ rb1, const float* __restrict__ rb2,
    const int* __restrict__ counts, const int* __restrict__ lists,
    const float* __restrict__ sscore,
    ushort* __restrict__ sbuf, float* __restrict__ y)
{
    const int bi  = blockIdx.x;
    const int tid = threadIdx.x;

    __shared__ int    toks[TB];
    __shared__ int    orow[TB];
    __shared__ float  tscs[TB];
    __shared__ ushort hlds[TB * HDIM];          // 64 KB, XOR-swizzled, stride 512B
    __shared__ ushort ostage[8 * 64 * OSW];     // 34.8 KB per-wave repack

    int e_full;
    const float *b1, *b2;

    if (bi < 64) {                            // shared experts: 32 tiles x 2
        e_full = bi >> 5;
        const int tile = bi & 31;
        if (tid < TB) {
            const int t = tile * TB + tid;
            toks[tid] = t;
            orow[tid] = ATOMIC ? t : t * NSLOT + e_full;
            tscs[tid] = 1.f;
        }
        b1 = sb1 + e_full * HDIM;  b2 = sb2 + e_full * DIM;
    } else {                                  // routed: bucket walk over counts
        const int j = bi - 64;
        const int b = j & 7, pos = j >> 3;
        int e = -1, tile = 0, accum = 0;
        #pragma unroll
        for (int g = 0; g < 4; ++g) {
            const int eg = b + 8 * g;
            const int tg = (counts[eg] + TB - 1) / TB;
            if (e < 0 && pos < accum + tg) { e = eg; tile = pos - accum; }
            accum += tg;
        }
        if (e < 0) return;
        e_full = N_SH + e;
        const int cnt = counts[e];
        if (tid < TB) {
            const int idx = tile * TB + tid;
            if (idx < cnt) {
                const int lv = lists[(size_t)e * T_TOK + idx];
                const int t = (lv >> 2) & (T_TOK - 1);
                toks[tid] = t;
                orow[tid] = ATOMIC ? t : t * NSLOT + 2 + (lv & 3);
                tscs[tid] = ATOMIC ? sscore[(size_t)t * NSLOT + 2 + (lv & 3)] : 0.f;
            } else {
                toks[tid] = 0;
                orow[tid] = ATOMIC ? 0 : T_TOK * NSLOT;   // dummy row
                tscs[tid] = 0.f;
            }
        }
        b1 = rb1 + e * HDIM;  b2 = rb2 + e * DIM;
    }
    __syncthreads();

    const int w = tid >> 6, lane = tid & 63;
    const int l16 = lane & 15, lk = lane >> 4;

    const ushort* W1e = W1p + (size_t)e_full * DIM * HDIM;
    const ushort* W2e = W2p + (size_t)e_full * HDIM * DIM;

    // ---- phase 1: C1[128,256] = X @ W1, one pass, wave tile M32 x N128 ----
    {
        const int mq = w >> 1;
        const int nh = w & 1;

        const ushort* abase[2];
        #pragma unroll
        for (int mi = 0; mi < 2; ++mi)
            abase[mi] = xnb + (size_t)toks[mq * 32 + mi * 16 + l16] * DIM + lk * 8;

        const ushort* bbase[8];
        #pragma unroll
        for (int ni = 0; ni < 8; ++ni)
            bbase[ni] = W1e + (size_t)((nh * 8 + ni) * 32) * 512 + lane * 8;

        f32x4 acc[2][8];
        #pragma unroll
        for (int mi = 0; mi < 2; ++mi)
            #pragma unroll
            for (int ni = 0; ni < 8; ++ni) acc[mi][ni] = (f32x4){0.f,0.f,0.f,0.f};

        bf16x8 ac[2], bc[8];
        #pragma unroll
        for (int mi = 0; mi < 2; ++mi) ac[mi] = *(const bf16x8*)abase[mi];
        #pragma unroll
        for (int ni = 0; ni < 8; ++ni) bc[ni] = *(const bf16x8*)bbase[ni];

        #pragma unroll
        for (int k32 = 0; k32 < 32; ++k32) {
            bf16x8 an[2], bn[8];
            if (k32 < 31) {
                #pragma unroll
                for (int ni = 0; ni < 8; ++ni)
                    bn[ni] = *(const bf16x8*)(bbase[ni] + (size_t)(k32 + 1) * 512);
                #pragma unroll
                for (int mi = 0; mi < 2; ++mi)
                    an[mi] = *(const bf16x8*)(abase[mi] + (k32 + 1) * 32);
            }
            #pragma unroll
            for (int ni = 0; ni < 8; ++ni)
                #pragma unroll
                for (int mi = 0; mi < 2; ++mi)
                    acc[mi][ni] = __builtin_amdgcn_mfma_f32_16x16x32_bf16(ac[mi], bc[ni], acc[mi][ni], 0, 0, 0);
            if (k32 < 31) {
                #pragma unroll
                for (int ni = 0; ni < 8; ++ni) bc[ni] = bn[ni];
                #pragma unroll
                for (int mi = 0; mi < 2; ++mi) ac[mi] = an[mi];
            }
        }

        #pragma unroll
        for (int ni = 0; ni < 8; ++ni) {
            const int n = nh * 128 + ni * 16 + l16;
            const float bv = b1[n];
            #pragma unroll
            for (int mi = 0; mi < 2; ++mi) {
                #pragma unroll
                for (int r = 0; r < 4; ++r) {
                    const int m = mq * 32 + mi * 16 + lk * 4 + r;
                    const int byte = (m * (HDIM * 2) + n * 2) ^ ((m & 7) << 4);
                    *(ushort*)((char*)hlds + byte) = f2b(acc[mi][ni][r] + bv);
                }
            }
        }
    }
    __syncthreads();

    // ---- phase 2: C2[128,1024] = h @ W2, 4 jc chunks x 8 k-steps ----
    {
        const int mh = w >> 2;
        const int nq = w & 3;

        for (int jc = 0; jc < 4; ++jc) {
            f32x4 acc2[4][4];
            #pragma unroll
            for (int mi = 0; mi < 4; ++mi)
                #pragma unroll
                for (int ni = 0; ni < 4; ++ni) acc2[mi][ni] = (f32x4){0.f,0.f,0.f,0.f};

            const ushort* b2base[4];
            #pragma unroll
            for (int ni = 0; ni < 4; ++ni)
                b2base[ni] = W2e + (size_t)((jc * 16 + nq * 4 + ni) * 8) * 512 + lane * 8;

            bf16x8 bc2[4];
            #pragma unroll
            for (int ni = 0; ni < 4; ++ni) bc2[ni] = *(const bf16x8*)b2base[ni];

            #pragma unroll
            for (int k32 = 0; k32 < 8; ++k32) {
                bf16x8 a2[4];
                #pragma unroll
                for (int mi = 0; mi < 4; ++mi) {
                    const int m = mh * 64 + mi * 16 + l16;
                    const int byte = (m * (HDIM * 2) + (k32 * 32 + lk * 8) * 2) ^ ((m & 7) << 4);
                    a2[mi] = *(const bf16x8*)((const char*)hlds + byte);
                }
                bf16x8 bn2[4];
                if (k32 < 7) {
                    #pragma unroll
                    for (int ni = 0; ni < 4; ++ni)
                        bn2[ni] = *(const bf16x8*)(b2base[ni] + (size_t)(k32 + 1) * 512);
                }
                #pragma unroll
                for (int ni = 0; ni < 4; ++ni)
                    #pragma unroll
                    for (int mi = 0; mi < 4; ++mi)
                        acc2[mi][ni] = __builtin_amdgcn_mfma_f32_16x16x32_bf16(a2[mi], bc2[ni], acc2[mi][ni], 0, 0, 0);
                if (k32 < 7) {
                    #pragma unroll
                    for (int ni = 0; ni < 4; ++ni) bc2[ni] = bn2[ni];
                }
            }

            if (ATOMIC) {
                #pragma unroll
                for (int ni = 0; ni < 4; ++ni) {
                    const int n = jc * 256 + nq * 64 + ni * 16 + l16;
                    const float bv = b2[n];
                    #pragma unroll
                    for (int mi = 0; mi < 4; ++mi)
                        #pragma unroll
                        for (int r = 0; r < 4; ++r) {
                            const int m = mi * 16 + lk * 4 + r;
                            const float val = gelu_tanh(acc2[mi][ni][r] + bv) * tscs[mh * 64 + m];
                            atomicAdd(&y[(size_t)orow[mh * 64 + m] * DIM + n], val);
                        }
                }
            } else {
                ushort* os = ostage + w * (64 * OSW);
                #pragma unroll
                for (int p = 0; p < 2; ++p) {
                    asm volatile("s_waitcnt lgkmcnt(0)" ::: "memory");
                    #pragma unroll
                    for (int q = 0; q < 2; ++q) {
                        const int ni = p * 2 + q;
                        const float bv = b2[jc * 256 + nq * 64 + ni * 16 + l16];
                        #pragma unroll
                        for (int mi = 0; mi < 4; ++mi)
                            #pragma unroll
                            for (int r = 0; r < 4; ++r) {
                                const int m = mi * 16 + lk * 4 + r;
                                os[m * OSW + q * 16 + l16] = f2b(acc2[mi][ni][r] + bv);
                            }
                    }
                    asm volatile("s_waitcnt lgkmcnt(0)" ::: "memory");
                    #pragma unroll
                    for (int rr = 0; rr < 4; ++rr) {
                        const int m  = rr * 16 + (lane >> 2);
                        const int nl = (lane & 3) * 8;
                        u16x8 vv = *(const u16x8*)(os + m * OSW + nl);
                        *(u16x8*)(sbuf + (size_t)orow[mh * 64 + m] * DIM
                                  + jc * 256 + nq * 64 + p * 32 + nl) = vv;
                    }
                }
            }
        }
    }
}

// ---------------- gather: y = bf16(xn) + sum_s gelu(slot)*score ----------------
__global__ __launch_bounds__(256) void gather_kernel(
    const ushort* __restrict__ sbuf, const float* __restrict__ sscore,
    const ushort* __restrict__ xnb, float* __restrict__ y)
{
    const int idx = blockIdx.x * 256 + threadIdx.x;
    const int t = idx >> 8;
    const int d = (idx & 255) * 4;
    const ushort4 xr = *(const ushort4*)(xnb + (size_t)t * DIM + d);
    float4 a;
    a.x = b2f(xr.x); a.y = b2f(xr.y); a.z = b2f(xr.z); a.w = b2f(xr.w);
    #pragma unroll
    for (int s = 0; s < NSLOT; ++s) {
        const float sc = sscore[(size_t)t * NSLOT + s];
        const ushort4 u = *(const ushort4*)(sbuf + ((size_t)t * NSLOT + s) * DIM + d);
        a.x += gelu_tanh(b2f(u.x)) * sc;
        a.y += gelu_tanh(b2f(u.y)) * sc;
        a.z += gelu_tanh(b2f(u.z)) * sc;
        a.w += gelu_tanh(b2f(u.w)) * sc;
    }
    ((float4*)y)[idx] = a;
}

extern "C" void kernel_launch(void* const* d_in, const int* in_sizes, int n_in,
                              void* d_out, int out_size, void* d_ws, size_t ws_size,
                              hipStream_t stream) {
    const float* x      = (const float*)d_in[0];
    const float* rms_w  = (const float*)d_in[1];
    const float* cent   = (const float*)d_in[2];
    const float* sW1    = (const float*)d_in[3];
    const float* sb1    = (const float*)d_in[4];
    const float* sW2    = (const float*)d_in[5];
    const float* sb2    = (const float*)d_in[6];
    const float* rW1    = (const float*)d_in[7];
    const float* rb1    = (const float*)d_in[8];
    const float* rW2    = (const float*)d_in[9];
    const float* rb2    = (const float*)d_in[10];

    float* y_out   = (float*)d_out;
    float* aff_out = (float*)d_out + (size_t)T_TOK * DIM;

    char* p = (char*)d_ws;
    size_t off = 0;
    auto take = [&](size_t b) {
        char* r = p + off;
        off += (b + 255) & ~(size_t)255;
        return r;
    };
    ushort* xnb    = (ushort*)take((size_t)T_TOK * DIM * 2);
    ushort* W1p    = (ushort*)take((size_t)N_E * DIM * HDIM * 2);
    ushort* W2p    = (ushort*)take((size_t)N_E * HDIM * DIM * 2);
    int*    counts = (int*)take(N_RT * sizeof(int));
    int*    lists  = (int*)take((size_t)N_RT * T_TOK * 4);
    float*  sscore = (float*)take((size_t)T_TOK * NSLOT * 4);
    int*    tk_e   = (int*)take((size_t)T_TOK * TOPK * 4);
    ushort* sbuf   = (ushort*)take(((size_t)T_TOK * NSLOT + TB) * DIM * 2);
    const bool slot_ok = (off <= ws_size);

    fused_pre<<<dim3(PREB), dim3(256), 0, stream>>>(
        x, rms_w, cent, sW1, rW1, sW2, rW2, W1p, W2p,
        xnb, aff_out, tk_e, sscore);

    scatter_kernel<<<dim3(N_RT), dim3(64), 0, stream>>>(tk_e, counts, lists);

    const int grid = 64 + 8 * MAXPB;
    if (slot_ok) {
        moe_mfma<false><<<dim3(grid), dim3(512), 0, stream>>>(
            xnb, W1p, W2p, sb1, sb2, rb1, rb2, counts, lists,
            sscore, sbuf, y_out);
        gather_kernel<<<dim3((T_TOK * DIM / 4) / 256), dim3(256), 0, stream>>>(
            sbuf, sscore, xnb, y_out);
    } else {
        residual_init<<<dim3((T_TOK * DIM / 4) / 256), dim3(256), 0, stream>>>(
            xnb, y_out);
        moe_mfma<true><<<dim3(grid), dim3(512), 0, stream>>>(
            xnb, W1p, W2p, sb1, sb2, rb1, rb2, counts, lists,
            sscore, sbuf, y_out);
    }
}

// Round 16
// 159.965 us; speedup vs baseline: 1.5188x; 1.5188x over previous
//
#include <hip/hip_runtime.h>
#include <hip/hip_bf16.h>
#include <math.h>

#define T_TOK 4096
#define DIM   1024
#define HDIM  256
#define N_SH  2
#define N_RT  32
#define N_E   34
#define TOPK  4
#define TB    128
#define MAXPB 200
#define NSLOT 6
#define OSW   34          // ostage row stride (32 cols + 2 pad)

typedef short bf16x8 __attribute__((ext_vector_type(8)));
typedef float f32x4  __attribute__((ext_vector_type(4)));
typedef unsigned short u16x8 __attribute__((ext_vector_type(8)));

__device__ __forceinline__ ushort f2b(float v) {
    __hip_bfloat16 h = __float2bfloat16(v);
    return *reinterpret_cast<const ushort*>(&h);
}
__device__ __forceinline__ float b2f(ushort u) {
    unsigned int x = ((unsigned int)u) << 16;
    return __uint_as_float(x);
}
__device__ __forceinline__ float gelu_tanh(float x) {
    float z = 0.7978845608028654f * (x + 0.044715f * x * x * x);
    float e = __expf(2.0f * z);
    float t = 1.0f - 2.0f / (e + 1.0f);
    return 0.5f * x * (1.0f + t);
}

// ---- pack weights v2: coalesced LDS-transpose ----
// block: expert e = blockIdx.y, k-slab k32 = blockIdx.x % (K/32),
// n-chunk nc = blockIdx.x / (K/32) (128 cols). Output layout identical to v1:
// dst[e*K*N + tile*512 + lane*8 + j], tile = n16*(K/32)+k32, lane = lk*16+l16,
// element = W[k32*32 + lk*8 + j][n16*16 + l16].
template<int K, int N>
__global__ __launch_bounds__(256) void pack_weights(
    const float* __restrict__ srcS, const float* __restrict__ srcR,
    ushort* __restrict__ dst)
{
    const int e = blockIdx.y;
    const float* src = (e < N_SH) ? (srcS + (size_t)e * K * N)
                                  : (srcR + (size_t)(e - N_SH) * K * N);
    const int kt  = K / 32;
    const int k32 = blockIdx.x % kt;
    const int nc  = blockIdx.x / kt;
    const int tid = threadIdx.x;

    __shared__ ushort ls[32][137];   // 32 rows (k) x 128 cols (n), pad to 137

    // stage: coalesced float4 reads (512B contiguous per row-segment)
    #pragma unroll
    for (int it = 0; it < 4; ++it) {
        const int row = it * 8 + (tid >> 5);
        const int c4  = tid & 31;
        const float4 v = *(const float4*)(src + (size_t)(k32 * 32 + row) * N
                                          + nc * 128 + c4 * 4);
        ls[row][c4 * 4 + 0] = f2b(v.x);
        ls[row][c4 * 4 + 1] = f2b(v.y);
        ls[row][c4 * 4 + 2] = f2b(v.z);
        ls[row][c4 * 4 + 3] = f2b(v.w);
    }
    __syncthreads();

    // emit 8 packed tiles (n16 = nc*8 + t8); stores are 512B-contiguous per tile
    #pragma unroll
    for (int it = 0; it < 2; ++it) {
        const int t8   = tid >> 5;
        const int lane = it * 32 + (tid & 31);
        const int l16 = lane & 15, lk = lane >> 4;
        u16x8 o;
        #pragma unroll
        for (int j = 0; j < 8; ++j)
            o[j] = ls[lk * 8 + j][t8 * 16 + l16];
        const size_t tile = (size_t)(nc * 8 + t8) * kt + k32;
        *(u16x8*)(dst + (size_t)e * K * N + tile * 512 + lane * 8) = o;
    }
}

// ---------------- RMSNorm + router, 4 tokens per block ----------------
__global__ __launch_bounds__(256) void rms_router_kernel(
    const float* __restrict__ x, const float* __restrict__ rms_w,
    const float* __restrict__ cent,
    ushort* __restrict__ xnb, float* __restrict__ aff_out,
    int* __restrict__ tk_e, float* __restrict__ sscore)
{
    const int t0  = blockIdx.x * 4;
    const int tid = threadIdx.x;
    const int wid = tid >> 6;
    const int lane = tid & 63;
    const int t = t0 + wid;

    __shared__ float xsh[4][DIM];
    __shared__ float logits[4][N_RT];

    float4 xv[4], wv[4];
    float ss = 0.f;
    #pragma unroll
    for (int q = 0; q < 4; ++q) {
        xv[q] = ((const float4*)(x + (size_t)t * DIM))[lane + 64 * q];
        ss += xv[q].x*xv[q].x + xv[q].y*xv[q].y + xv[q].z*xv[q].z + xv[q].w*xv[q].w;
    }
    #pragma unroll
    for (int o = 32; o > 0; o >>= 1) ss += __shfl_down(ss, o);
    const float rstd = rsqrtf(__shfl(ss, 0) * (1.0f / (float)DIM) + 1e-6f);

    #pragma unroll
    for (int q = 0; q < 4; ++q)
        wv[q] = ((const float4*)rms_w)[lane + 64 * q];

    #pragma unroll
    for (int q = 0; q < 4; ++q) {
        float4 nv;
        nv.x = xv[q].x * rstd * wv[q].x;
        nv.y = xv[q].y * rstd * wv[q].y;
        nv.z = xv[q].z * rstd * wv[q].z;
        nv.w = xv[q].w * rstd * wv[q].w;
        ushort4 xb = make_ushort4(f2b(nv.x), f2b(nv.y), f2b(nv.z), f2b(nv.w));
        ((ushort4*)(xnb + (size_t)t * DIM))[lane + 64 * q] = xb;
        ((float4*)xsh[wid])[lane + 64 * q] = nv;
    }
    __syncthreads();

    #pragma unroll
    for (int ei = 0; ei < 8; ++ei) {
        const int e = wid * 8 + ei;
        const float4* c4 = (const float4*)(cent + (size_t)e * DIM);
        float a0 = 0.f, a1 = 0.f, a2 = 0.f, a3 = 0.f;
        #pragma unroll
        for (int q = 0; q < 4; ++q) {
            const float4 cv = c4[lane + 64 * q];
            const float4 x0 = ((const float4*)xsh[0])[lane + 64 * q];
            const float4 x1 = ((const float4*)xsh[1])[lane + 64 * q];
            const float4 x2 = ((const float4*)xsh[2])[lane + 64 * q];
            const float4 x3 = ((const float4*)xsh[3])[lane + 64 * q];
            a0 += cv.x*x0.x + cv.y*x0.y + cv.z*x0.z + cv.w*x0.w;
            a1 += cv.x*x1.x + cv.y*x1.y + cv.z*x1.z + cv.w*x1.w;
            a2 += cv.x*x2.x + cv.y*x2.y + cv.z*x2.z + cv.w*x2.w;
            a3 += cv.x*x3.x + cv.y*x3.y + cv.z*x3.z + cv.w*x3.w;
        }
        #pragma unroll
        for (int o = 32; o > 0; o >>= 1) {
            a0 += __shfl_down(a0, o);
            a1 += __shfl_down(a1, o);
            a2 += __shfl_down(a2, o);
            a3 += __shfl_down(a3, o);
        }
        if (lane == 0) {
            logits[0][e] = a0; logits[1][e] = a1;
            logits[2][e] = a2; logits[3][e] = a3;
        }
    }
    __syncthreads();

    {
        float v = (lane < N_RT) ? logits[wid][lane] : -INFINITY;
        float m = v;
        #pragma unroll
        for (int o = 32; o > 0; o >>= 1) m = fmaxf(m, __shfl_xor(m, o));
        float p = (lane < N_RT) ? expf(v - m) : 0.f;
        float s = p;
        #pragma unroll
        for (int o = 32; o > 0; o >>= 1) s += __shfl_xor(s, o);
        const float a = p / s;
        if (lane < N_RT) aff_out[(size_t)t * N_RT + lane] = a;
        if (lane < N_SH) sscore[(size_t)t * NSLOT + lane] = 1.f;

        float vv = (lane < N_RT) ? a : -1.f;
        #pragma unroll
        for (int it = 0; it < TOPK; ++it) {
            float mx = vv;
            #pragma unroll
            for (int o = 32; o > 0; o >>= 1) mx = fmaxf(mx, __shfl_xor(mx, o));
            unsigned long long msk = __ballot(vv == mx);
            int sel = __ffsll((long long)msk) - 1;
            sel = (sel < 0) ? 0 : (sel & (N_RT - 1));
            if (lane == 0) {
                tk_e[(size_t)t * TOPK + it] = sel;
                sscore[(size_t)t * NSLOT + 2 + it] = mx;
            }
            if (lane == sel) vv = -1.f;
        }
    }
}

// ---- scatter: block e compacts (token,slot) entries where tk_e == e ----
__global__ __launch_bounds__(64) void scatter_kernel(
    const int* __restrict__ tk_e, int* __restrict__ counts, int* __restrict__ lists)
{
    const int e    = blockIdx.x;
    const int lane = threadIdx.x;
    const unsigned long long lt = (1ull << lane) - 1ull;
    int base = 0;
    int* lst = lists + (size_t)e * T_TOK;
    for (int c = 0; c < T_TOK * TOPK; c += 256) {
        const int4 v = *(const int4*)(tk_e + c + lane * 4);
        const bool p0 = (v.x == e), p1 = (v.y == e), p2 = (v.z == e), p3 = (v.w == e);
        const unsigned long long m0 = __ballot(p0);
        const unsigned long long m1 = __ballot(p1);
        const unsigned long long m2 = __ballot(p2);
        const unsigned long long m3 = __ballot(p3);
        const int c0 = __popcll(m0), c1 = __popcll(m1), c2 = __popcll(m2);
        if (p0) lst[base + __popcll(m0 & lt)] = c + lane * 4 + 0;
        if (p1) lst[base + c0 + __popcll(m1 & lt)] = c + lane * 4 + 1;
        if (p2) lst[base + c0 + c1 + __popcll(m2 & lt)] = c + lane * 4 + 2;
        if (p3) lst[base + c0 + c1 + c2 + __popcll(m3 & lt)] = c + lane * 4 + 3;
        base += c0 + c1 + c2 + __popcll(m3);
    }
    if (lane == 0) counts[e] = base;
}

// ---- residual init (fallback path only): y = bf16(xn) ----
__global__ __launch_bounds__(256) void residual_init(
    const ushort* __restrict__ xnb, float* __restrict__ y)
{
    const int idx = blockIdx.x * 256 + threadIdx.x;
    const ushort4 xr = *(const ushort4*)(xnb + (size_t)idx * 4);
    float4 a;
    a.x = b2f(xr.x); a.y = b2f(xr.y); a.z = b2f(xr.z); a.w = b2f(xr.w);
    ((float4*)y)[idx] = a;
}

// ---------------- fused 2-layer expert MLP (r13-verified structure) ----------------
// Phase 1 (K=1024): wave (mq=w>>1, nh=w&1): M=32, N=128, 16 MFMA/step.
// Phase 2 (K=256): wave (mh=w>>2, nq=w&3): M=64, N=64, 16 MFMA/step, 4 jc chunks.
// Routed blocks derive (expert, tile) from counts directly.
template<bool ATOMIC>
__global__ __launch_bounds__(512, 2) void moe_mfma(
    const ushort* __restrict__ xnb,
    const ushort* __restrict__ W1p, const ushort* __restrict__ W2p,
    const float* __restrict__ sb1, const float* __restrict__ sb2,
    const float* __restrict__ rb1, const float* __restrict__ rb2,
    const int* __restrict__ counts, const int* __restrict__ lists,
    const float* __restrict__ sscore,
    ushort* __restrict__ sbuf, float* __restrict__ y)
{
    const int bi  = blockIdx.x;
    const int tid = threadIdx.x;

    __shared__ int    toks[TB];
    __shared__ int    orow[TB];
    __shared__ float  tscs[TB];
    __shared__ ushort hlds[TB * HDIM];          // 64 KB, XOR-swizzled, stride 512B
    __shared__ ushort ostage[8 * 64 * OSW];     // 34.8 KB per-wave repack

    int e_full;
    const float *b1, *b2;

    if (bi < 64) {                            // shared experts: 32 tiles x 2
        e_full = bi >> 5;
        const int tile = bi & 31;
        if (tid < TB) {
            const int t = tile * TB + tid;
            toks[tid] = t;
            orow[tid] = ATOMIC ? t : t * NSLOT + e_full;
            tscs[tid] = 1.f;
        }
        b1 = sb1 + e_full * HDIM;  b2 = sb2 + e_full * DIM;
    } else {                                  // routed: bucket walk over counts
        const int j = bi - 64;
        const int b = j & 7, pos = j >> 3;
        int e = -1, tile = 0, accum = 0;
        #pragma unroll
        for (int g = 0; g < 4; ++g) {
            const int eg = b + 8 * g;
            const int tg = (counts[eg] + TB - 1) / TB;
            if (e < 0 && pos < accum + tg) { e = eg; tile = pos - accum; }
            accum += tg;
        }
        if (e < 0) return;
        e_full = N_SH + e;
        const int cnt = counts[e];
        if (tid < TB) {
            const int idx = tile * TB + tid;
            if (idx < cnt) {
                const int lv = lists[(size_t)e * T_TOK + idx];
                const int t = (lv >> 2) & (T_TOK - 1);
                toks[tid] = t;
                orow[tid] = ATOMIC ? t : t * NSLOT + 2 + (lv & 3);
                tscs[tid] = ATOMIC ? sscore[(size_t)t * NSLOT + 2 + (lv & 3)] : 0.f;
            } else {
                toks[tid] = 0;
                orow[tid] = ATOMIC ? 0 : T_TOK * NSLOT;   // dummy row
                tscs[tid] = 0.f;
            }
        }
        b1 = rb1 + e * HDIM;  b2 = rb2 + e * DIM;
    }
    __syncthreads();

    const int w = tid >> 6, lane = tid & 63;
    const int l16 = lane & 15, lk = lane >> 4;

    const ushort* W1e = W1p + (size_t)e_full * DIM * HDIM;
    const ushort* W2e = W2p + (size_t)e_full * HDIM * DIM;

    // ---- phase 1: C1[128,256] = X @ W1, one pass, wave tile M32 x N128 ----
    {
        const int mq = w >> 1;
        const int nh = w & 1;

        const ushort* abase[2];
        #pragma unroll
        for (int mi = 0; mi < 2; ++mi)
            abase[mi] = xnb + (size_t)toks[mq * 32 + mi * 16 + l16] * DIM + lk * 8;

        const ushort* bbase[8];
        #pragma unroll
        for (int ni = 0; ni < 8; ++ni)
            bbase[ni] = W1e + (size_t)((nh * 8 + ni) * 32) * 512 + lane * 8;

        f32x4 acc[2][8];
        #pragma unroll
        for (int mi = 0; mi < 2; ++mi)
            #pragma unroll
            for (int ni = 0; ni < 8; ++ni) acc[mi][ni] = (f32x4){0.f,0.f,0.f,0.f};

        bf16x8 ac[2], bc[8];
        #pragma unroll
        for (int mi = 0; mi < 2; ++mi) ac[mi] = *(const bf16x8*)abase[mi];
        #pragma unroll
        for (int ni = 0; ni < 8; ++ni) bc[ni] = *(const bf16x8*)bbase[ni];

        #pragma unroll
        for (int k32 = 0; k32 < 32; ++k32) {
            bf16x8 an[2], bn[8];
            if (k32 < 31) {
                #pragma unroll
                for (int ni = 0; ni < 8; ++ni)
                    bn[ni] = *(const bf16x8*)(bbase[ni] + (size_t)(k32 + 1) * 512);
                #pragma unroll
                for (int mi = 0; mi < 2; ++mi)
                    an[mi] = *(const bf16x8*)(abase[mi] + (k32 + 1) * 32);
            }
            #pragma unroll
            for (int ni = 0; ni < 8; ++ni)
                #pragma unroll
                for (int mi = 0; mi < 2; ++mi)
                    acc[mi][ni] = __builtin_amdgcn_mfma_f32_16x16x32_bf16(ac[mi], bc[ni], acc[mi][ni], 0, 0, 0);
            if (k32 < 31) {
                #pragma unroll
                for (int ni = 0; ni < 8; ++ni) bc[ni] = bn[ni];
                #pragma unroll
                for (int mi = 0; mi < 2; ++mi) ac[mi] = an[mi];
            }
        }

        #pragma unroll
        for (int ni = 0; ni < 8; ++ni) {
            const int n = nh * 128 + ni * 16 + l16;
            const float bv = b1[n];
            #pragma unroll
            for (int mi = 0; mi < 2; ++mi) {
                #pragma unroll
                for (int r = 0; r < 4; ++r) {
                    const int m = mq * 32 + mi * 16 + lk * 4 + r;
                    const int byte = (m * (HDIM * 2) + n * 2) ^ ((m & 7) << 4);
                    *(ushort*)((char*)hlds + byte) = f2b(acc[mi][ni][r] + bv);
                }
            }
        }
    }
    __syncthreads();

    // ---- phase 2: C2[128,1024] = h @ W2, 4 jc chunks x 8 k-steps ----
    {
        const int mh = w >> 2;
        const int nq = w & 3;

        for (int jc = 0; jc < 4; ++jc) {
            f32x4 acc2[4][4];
            #pragma unroll
            for (int mi = 0; mi < 4; ++mi)
                #pragma unroll
                for (int ni = 0; ni < 4; ++ni) acc2[mi][ni] = (f32x4){0.f,0.f,0.f,0.f};

            const ushort* b2base[4];
            #pragma unroll
            for (int ni = 0; ni < 4; ++ni)
                b2base[ni] = W2e + (size_t)((jc * 16 + nq * 4 + ni) * 8) * 512 + lane * 8;

            bf16x8 bc2[4];
            #pragma unroll
            for (int ni = 0; ni < 4; ++ni) bc2[ni] = *(const bf16x8*)b2base[ni];

            #pragma unroll
            for (int k32 = 0; k32 < 8; ++k32) {
                bf16x8 a2[4];
                #pragma unroll
                for (int mi = 0; mi < 4; ++mi) {
                    const int m = mh * 64 + mi * 16 + l16;
                    const int byte = (m * (HDIM * 2) + (k32 * 32 + lk * 8) * 2) ^ ((m & 7) << 4);
                    a2[mi] = *(const bf16x8*)((const char*)hlds + byte);
                }
                bf16x8 bn2[4];
                if (k32 < 7) {
                    #pragma unroll
                    for (int ni = 0; ni < 4; ++ni)
                        bn2[ni] = *(const bf16x8*)(b2base[ni] + (size_t)(k32 + 1) * 512);
                }
                #pragma unroll
                for (int ni = 0; ni < 4; ++ni)
                    #pragma unroll
                    for (int mi = 0; mi < 4; ++mi)
                        acc2[mi][ni] = __builtin_amdgcn_mfma_f32_16x16x32_bf16(a2[mi], bc2[ni], acc2[mi][ni], 0, 0, 0);
                if (k32 < 7) {
                    #pragma unroll
                    for (int ni = 0; ni < 4; ++ni) bc2[ni] = bn2[ni];
                }
            }

            if (ATOMIC) {
                #pragma unroll
                for (int ni = 0; ni < 4; ++ni) {
                    const int n = jc * 256 + nq * 64 + ni * 16 + l16;
                    const float bv = b2[n];
                    #pragma unroll
                    for (int mi = 0; mi < 4; ++mi)
                        #pragma unroll
                        for (int r = 0; r < 4; ++r) {
                            const int m = mi * 16 + lk * 4 + r;
                            const float val = gelu_tanh(acc2[mi][ni][r] + bv) * tscs[mh * 64 + m];
                            atomicAdd(&y[(size_t)orow[mh * 64 + m] * DIM + n], val);
                        }
                }
            } else {
                ushort* os = ostage + w * (64 * OSW);
                #pragma unroll
                for (int p = 0; p < 2; ++p) {
                    asm volatile("s_waitcnt lgkmcnt(0)" ::: "memory");
                    #pragma unroll
                    for (int q = 0; q < 2; ++q) {
                        const int ni = p * 2 + q;
                        const float bv = b2[jc * 256 + nq * 64 + ni * 16 + l16];
                        #pragma unroll
                        for (int mi = 0; mi < 4; ++mi)
                            #pragma unroll
                            for (int r = 0; r < 4; ++r) {
                                const int m = mi * 16 + lk * 4 + r;
                                os[m * OSW + q * 16 + l16] = f2b(acc2[mi][ni][r] + bv);
                            }
                    }
                    asm volatile("s_waitcnt lgkmcnt(0)" ::: "memory");
                    #pragma unroll
                    for (int rr = 0; rr < 4; ++rr) {
                        const int m  = rr * 16 + (lane >> 2);
                        const int nl = (lane & 3) * 8;
                        u16x8 vv = *(const u16x8*)(os + m * OSW + nl);
                        *(u16x8*)(sbuf + (size_t)orow[mh * 64 + m] * DIM
                                  + jc * 256 + nq * 64 + p * 32 + nl) = vv;
                    }
                }
            }
        }
    }
}

// ---------------- gather: y = bf16(xn) + sum_s gelu(slot)*score ----------------
__global__ __launch_bounds__(256) void gather_kernel(
    const ushort* __restrict__ sbuf, const float* __restrict__ sscore,
    const ushort* __restrict__ xnb, float* __restrict__ y)
{
    const int idx = blockIdx.x * 256 + threadIdx.x;
    const int t = idx >> 8;
    const int d = (idx & 255) * 4;
    const ushort4 xr = *(const ushort4*)(xnb + (size_t)t * DIM + d);
    float4 a;
    a.x = b2f(xr.x); a.y = b2f(xr.y); a.z = b2f(xr.z); a.w = b2f(xr.w);
    #pragma unroll
    for (int s = 0; s < NSLOT; ++s) {
        const float sc = sscore[(size_t)t * NSLOT + s];
        const ushort4 u = *(const ushort4*)(sbuf + ((size_t)t * NSLOT + s) * DIM + d);
        a.x += gelu_tanh(b2f(u.x)) * sc;
        a.y += gelu_tanh(b2f(u.y)) * sc;
        a.z += gelu_tanh(b2f(u.z)) * sc;
        a.w += gelu_tanh(b2f(u.w)) * sc;
    }
    ((float4*)y)[idx] = a;
}

extern "C" void kernel_launch(void* const* d_in, const int* in_sizes, int n_in,
                              void* d_out, int out_size, void* d_ws, size_t ws_size,
                              hipStream_t stream) {
    const float* x      = (const float*)d_in[0];
    const float* rms_w  = (const float*)d_in[1];
    const float* cent   = (const float*)d_in[2];
    const float* sW1    = (const float*)d_in[3];
    const float* sb1    = (const float*)d_in[4];
    const float* sW2    = (const float*)d_in[5];
    const float* sb2    = (const float*)d_in[6];
    const float* rW1    = (const float*)d_in[7];
    const float* rb1    = (const float*)d_in[8];
    const float* rW2    = (const float*)d_in[9];
    const float* rb2    = (const float*)d_in[10];

    float* y_out   = (float*)d_out;
    float* aff_out = (float*)d_out + (size_t)T_TOK * DIM;

    char* p = (char*)d_ws;
    size_t off = 0;
    auto take = [&](size_t b) {
        char* r = p + off;
        off += (b + 255) & ~(size_t)255;
        return r;
    };
    ushort* xnb    = (ushort*)take((size_t)T_TOK * DIM * 2);
    ushort* W1p    = (ushort*)take((size_t)N_E * DIM * HDIM * 2);
    ushort* W2p    = (ushort*)take((size_t)N_E * HDIM * DIM * 2);
    int*    counts = (int*)take(N_RT * sizeof(int));
    int*    lists  = (int*)take((size_t)N_RT * T_TOK * 4);
    float*  sscore = (float*)take((size_t)T_TOK * NSLOT * 4);
    int*    tk_e   = (int*)take((size_t)T_TOK * TOPK * 4);
    ushort* sbuf   = (ushort*)take(((size_t)T_TOK * NSLOT + TB) * DIM * 2);
    const bool slot_ok = (off <= ws_size);

    // W1: K=1024 (32 slabs) x N=256 (2 chunks) = 64 blocks/expert
    pack_weights<DIM, HDIM><<<dim3(64, N_E), dim3(256), 0, stream>>>(sW1, rW1, W1p);
    // W2: K=256 (8 slabs) x N=1024 (8 chunks) = 64 blocks/expert
    pack_weights<HDIM, DIM><<<dim3(64, N_E), dim3(256), 0, stream>>>(sW2, rW2, W2p);

    rms_router_kernel<<<dim3(T_TOK / 4), dim3(256), 0, stream>>>(
        x, rms_w, cent, xnb, aff_out, tk_e, sscore);

    scatter_kernel<<<dim3(N_RT), dim3(64), 0, stream>>>(tk_e, counts, lists);

    const int grid = 64 + 8 * MAXPB;
    if (slot_ok) {
        moe_mfma<false><<<dim3(grid), dim3(512), 0, stream>>>(
            xnb, W1p, W2p, sb1, sb2, rb1, rb2, counts, lists,
            sscore, sbuf, y_out);
        gather_kernel<<<dim3((T_TOK * DIM / 4) / 256), dim3(256), 0, stream>>>(
            sbuf, sscore, xnb, y_out);
    } else {
        residual_init<<<dim3((T_TOK * DIM / 4) / 256), dim3(256), 0, stream>>>(
            xnb, y_out);
        moe_mfma<true><<<dim3(grid), dim3(512), 0, stream>>>(
            xnb, W1p, W2p, sb1, sb2, rb1, rb2, counts, lists,
            sscore, sbuf, y_out);
    }
}

// Round 17
// 157.571 us; speedup vs baseline: 1.5419x; 1.0152x over previous
//
#include <hip/hip_runtime.h>
#include <hip/hip_bf16.h>
#include <math.h>

#define T_TOK 4096
#define DIM   1024
#define HDIM  256
#define N_SH  2
#define N_RT  32
#define N_E   34
#define TOPK  4
#define TB    128
#define MAXPB 200
#define NSLOT 6
#define OSW   34          // ostage row stride (32 cols + 2 pad)

typedef short bf16x8 __attribute__((ext_vector_type(8)));
typedef float f32x4  __attribute__((ext_vector_type(4)));
typedef unsigned short u16x8 __attribute__((ext_vector_type(8)));

__device__ __forceinline__ ushort f2b(float v) {
    __hip_bfloat16 h = __float2bfloat16(v);
    return *reinterpret_cast<const ushort*>(&h);
}
__device__ __forceinline__ float b2f(ushort u) {
    unsigned int x = ((unsigned int)u) << 16;
    return __uint_as_float(x);
}
__device__ __forceinline__ float gelu_tanh(float x) {
    float z = 0.7978845608028654f * (x + 0.044715f * x * x * x);
    float e = __expf(2.0f * z);
    float t = 1.0f - 2.0f / (e + 1.0f);
    return 0.5f * x * (1.0f + t);
}

// ---- pack weights v2: coalesced LDS-transpose (r16-verified) ----
template<int K, int N>
__global__ __launch_bounds__(256) void pack_weights(
    const float* __restrict__ srcS, const float* __restrict__ srcR,
    ushort* __restrict__ dst)
{
    const int e = blockIdx.y;
    const float* src = (e < N_SH) ? (srcS + (size_t)e * K * N)
                                  : (srcR + (size_t)(e - N_SH) * K * N);
    const int kt  = K / 32;
    const int k32 = blockIdx.x % kt;
    const int nc  = blockIdx.x / kt;
    const int tid = threadIdx.x;

    __shared__ ushort ls[32][137];

    #pragma unroll
    for (int it = 0; it < 4; ++it) {
        const int row = it * 8 + (tid >> 5);
        const int c4  = tid & 31;
        const float4 v = *(const float4*)(src + (size_t)(k32 * 32 + row) * N
                                          + nc * 128 + c4 * 4);
        ls[row][c4 * 4 + 0] = f2b(v.x);
        ls[row][c4 * 4 + 1] = f2b(v.y);
        ls[row][c4 * 4 + 2] = f2b(v.z);
        ls[row][c4 * 4 + 3] = f2b(v.w);
    }
    __syncthreads();

    #pragma unroll
    for (int it = 0; it < 2; ++it) {
        const int t8   = tid >> 5;
        const int lane = it * 32 + (tid & 31);
        const int l16 = lane & 15, lk = lane >> 4;
        u16x8 o;
        #pragma unroll
        for (int j = 0; j < 8; ++j)
            o[j] = ls[lk * 8 + j][t8 * 16 + l16];
        const size_t tile = (size_t)(nc * 8 + t8) * kt + k32;
        *(u16x8*)(dst + (size_t)e * K * N + tile * 512 + lane * 8) = o;
    }
}

// ---------------- RMSNorm + router, 4 tokens per block ----------------
__global__ __launch_bounds__(256) void rms_router_kernel(
    const float* __restrict__ x, const float* __restrict__ rms_w,
    const float* __restrict__ cent,
    ushort* __restrict__ xnb, float* __restrict__ aff_out,
    int* __restrict__ tk_e, float* __restrict__ sscore)
{
    const int t0  = blockIdx.x * 4;
    const int tid = threadIdx.x;
    const int wid = tid >> 6;
    const int lane = tid & 63;
    const int t = t0 + wid;

    __shared__ float xsh[4][DIM];
    __shared__ float logits[4][N_RT];

    float4 xv[4], wv[4];
    float ss = 0.f;
    #pragma unroll
    for (int q = 0; q < 4; ++q) {
        xv[q] = ((const float4*)(x + (size_t)t * DIM))[lane + 64 * q];
        ss += xv[q].x*xv[q].x + xv[q].y*xv[q].y + xv[q].z*xv[q].z + xv[q].w*xv[q].w;
    }
    #pragma unroll
    for (int o = 32; o > 0; o >>= 1) ss += __shfl_down(ss, o);
    const float rstd = rsqrtf(__shfl(ss, 0) * (1.0f / (float)DIM) + 1e-6f);

    #pragma unroll
    for (int q = 0; q < 4; ++q)
        wv[q] = ((const float4*)rms_w)[lane + 64 * q];

    #pragma unroll
    for (int q = 0; q < 4; ++q) {
        float4 nv;
        nv.x = xv[q].x * rstd * wv[q].x;
        nv.y = xv[q].y * rstd * wv[q].y;
        nv.z = xv[q].z * rstd * wv[q].z;
        nv.w = xv[q].w * rstd * wv[q].w;
        ushort4 xb = make_ushort4(f2b(nv.x), f2b(nv.y), f2b(nv.z), f2b(nv.w));
        ((ushort4*)(xnb + (size_t)t * DIM))[lane + 64 * q] = xb;
        ((float4*)xsh[wid])[lane + 64 * q] = nv;
    }
    __syncthreads();

    #pragma unroll
    for (int ei = 0; ei < 8; ++ei) {
        const int e = wid * 8 + ei;
        const float4* c4 = (const float4*)(cent + (size_t)e * DIM);
        float a0 = 0.f, a1 = 0.f, a2 = 0.f, a3 = 0.f;
        #pragma unroll
        for (int q = 0; q < 4; ++q) {
            const float4 cv = c4[lane + 64 * q];
            const float4 x0 = ((const float4*)xsh[0])[lane + 64 * q];
            const float4 x1 = ((const float4*)xsh[1])[lane + 64 * q];
            const float4 x2 = ((const float4*)xsh[2])[lane + 64 * q];
            const float4 x3 = ((const float4*)xsh[3])[lane + 64 * q];
            a0 += cv.x*x0.x + cv.y*x0.y + cv.z*x0.z + cv.w*x0.w;
            a1 += cv.x*x1.x + cv.y*x1.y + cv.z*x1.z + cv.w*x1.w;
            a2 += cv.x*x2.x + cv.y*x2.y + cv.z*x2.z + cv.w*x2.w;
            a3 += cv.x*x3.x + cv.y*x3.y + cv.z*x3.z + cv.w*x3.w;
        }
        #pragma unroll
        for (int o = 32; o > 0; o >>= 1) {
            a0 += __shfl_down(a0, o);
            a1 += __shfl_down(a1, o);
            a2 += __shfl_down(a2, o);
            a3 += __shfl_down(a3, o);
        }
        if (lane == 0) {
            logits[0][e] = a0; logits[1][e] = a1;
            logits[2][e] = a2; logits[3][e] = a3;
        }
    }
    __syncthreads();

    {
        float v = (lane < N_RT) ? logits[wid][lane] : -INFINITY;
        float m = v;
        #pragma unroll
        for (int o = 32; o > 0; o >>= 1) m = fmaxf(m, __shfl_xor(m, o));
        float p = (lane < N_RT) ? expf(v - m) : 0.f;
        float s = p;
        #pragma unroll
        for (int o = 32; o > 0; o >>= 1) s += __shfl_xor(s, o);
        const float a = p / s;
        if (lane < N_RT) aff_out[(size_t)t * N_RT + lane] = a;
        if (lane < N_SH) sscore[(size_t)t * NSLOT + lane] = 1.f;

        float vv = (lane < N_RT) ? a : -1.f;
        #pragma unroll
        for (int it = 0; it < TOPK; ++it) {
            float mx = vv;
            #pragma unroll
            for (int o = 32; o > 0; o >>= 1) mx = fmaxf(mx, __shfl_xor(mx, o));
            unsigned long long msk = __ballot(vv == mx);
            int sel = __ffsll((long long)msk) - 1;
            sel = (sel < 0) ? 0 : (sel & (N_RT - 1));
            if (lane == 0) {
                tk_e[(size_t)t * TOPK + it] = sel;
                sscore[(size_t)t * NSLOT + 2 + it] = mx;
            }
            if (lane == sel) vv = -1.f;
        }
    }
}

// ---- scatter: block e compacts (token,slot) entries where tk_e == e ----
__global__ __launch_bounds__(64) void scatter_kernel(
    const int* __restrict__ tk_e, int* __restrict__ counts, int* __restrict__ lists)
{
    const int e    = blockIdx.x;
    const int lane = threadIdx.x;
    const unsigned long long lt = (1ull << lane) - 1ull;
    int base = 0;
    int* lst = lists + (size_t)e * T_TOK;
    for (int c = 0; c < T_TOK * TOPK; c += 256) {
        const int4 v = *(const int4*)(tk_e + c + lane * 4);
        const bool p0 = (v.x == e), p1 = (v.y == e), p2 = (v.z == e), p3 = (v.w == e);
        const unsigned long long m0 = __ballot(p0);
        const unsigned long long m1 = __ballot(p1);
        const unsigned long long m2 = __ballot(p2);
        const unsigned long long m3 = __ballot(p3);
        const int c0 = __popcll(m0), c1 = __popcll(m1), c2 = __popcll(m2);
        if (p0) lst[base + __popcll(m0 & lt)] = c + lane * 4 + 0;
        if (p1) lst[base + c0 + __popcll(m1 & lt)] = c + lane * 4 + 1;
        if (p2) lst[base + c0 + c1 + __popcll(m2 & lt)] = c + lane * 4 + 2;
        if (p3) lst[base + c0 + c1 + c2 + __popcll(m3 & lt)] = c + lane * 4 + 3;
        base += c0 + c1 + c2 + __popcll(m3);
    }
    if (lane == 0) counts[e] = base;
}

// ---- residual init (fallback path only): y = bf16(xn) ----
__global__ __launch_bounds__(256) void residual_init(
    const ushort* __restrict__ xnb, float* __restrict__ y)
{
    const int idx = blockIdx.x * 256 + threadIdx.x;
    const ushort4 xr = *(const ushort4*)(xnb + (size_t)idx * 4);
    float4 a;
    a.x = b2f(xr.x); a.y = b2f(xr.y); a.z = b2f(xr.z); a.w = b2f(xr.w);
    ((float4*)y)[idx] = a;
}

// ---------------- fused 2-layer expert MLP ----------------
// Phase 1 (K=1024): wave (mh=w>>2, nq=w&3): M=64, N=64, 16 MFMA/step
//   (balanced tile: 8KB/step/wave vs 10KB for M32xN128 -> block 64KB/step vs 80KB).
// Phase 2 (K=256): wave (mh=w>>2, nq=w&3): M=64, N=64, 16 MFMA/step, 4 jc chunks.
template<bool ATOMIC>
__global__ __launch_bounds__(512, 2) void moe_mfma(
    const ushort* __restrict__ xnb,
    const ushort* __restrict__ W1p, const ushort* __restrict__ W2p,
    const float* __restrict__ sb1, const float* __restrict__ sb2,
    const float* __restrict__ rb1, const float* __restrict__ rb2,
    const int* __restrict__ counts, const int* __restrict__ lists,
    const float* __restrict__ sscore,
    ushort* __restrict__ sbuf, float* __restrict__ y)
{
    const int bi  = blockIdx.x;
    const int tid = threadIdx.x;

    __shared__ int    toks[TB];
    __shared__ int    orow[TB];
    __shared__ float  tscs[TB];
    __shared__ ushort hlds[TB * HDIM];          // 64 KB, XOR-swizzled, stride 512B
    __shared__ ushort ostage[8 * 64 * OSW];     // 34.8 KB per-wave repack

    int e_full;
    const float *b1, *b2;

    if (bi < 64) {                            // shared experts: 32 tiles x 2
        e_full = bi >> 5;
        const int tile = bi & 31;
        if (tid < TB) {
            const int t = tile * TB + tid;
            toks[tid] = t;
            orow[tid] = ATOMIC ? t : t * NSLOT + e_full;
            tscs[tid] = 1.f;
        }
        b1 = sb1 + e_full * HDIM;  b2 = sb2 + e_full * DIM;
    } else {                                  // routed: bucket walk over counts
        const int j = bi - 64;
        const int b = j & 7, pos = j >> 3;
        int e = -1, tile = 0, accum = 0;
        #pragma unroll
        for (int g = 0; g < 4; ++g) {
            const int eg = b + 8 * g;
            const int tg = (counts[eg] + TB - 1) / TB;
            if (e < 0 && pos < accum + tg) { e = eg; tile = pos - accum; }
            accum += tg;
        }
        if (e < 0) return;
        e_full = N_SH + e;
        const int cnt = counts[e];
        if (tid < TB) {
            const int idx = tile * TB + tid;
            if (idx < cnt) {
                const int lv = lists[(size_t)e * T_TOK + idx];
                const int t = (lv >> 2) & (T_TOK - 1);
                toks[tid] = t;
                orow[tid] = ATOMIC ? t : t * NSLOT + 2 + (lv & 3);
                tscs[tid] = ATOMIC ? sscore[(size_t)t * NSLOT + 2 + (lv & 3)] : 0.f;
            } else {
                toks[tid] = 0;
                orow[tid] = ATOMIC ? 0 : T_TOK * NSLOT;   // dummy row
                tscs[tid] = 0.f;
            }
        }
        b1 = rb1 + e * HDIM;  b2 = rb2 + e * DIM;
    }
    __syncthreads();

    const int w = tid >> 6, lane = tid & 63;
    const int l16 = lane & 15, lk = lane >> 4;
    const int mh = w >> 2;          // token half (64 rows)
    const int nq = w & 3;           // N quarter (64 cols)

    const ushort* W1e = W1p + (size_t)e_full * DIM * HDIM;
    const ushort* W2e = W2p + (size_t)e_full * HDIM * DIM;

    // ---- phase 1: C1[128,256] = X @ W1, wave tile M64 x N64 ----
    {
        const ushort* abase[4];
        #pragma unroll
        for (int mi = 0; mi < 4; ++mi)
            abase[mi] = xnb + (size_t)toks[mh * 64 + mi * 16 + l16] * DIM + lk * 8;

        const ushort* bbase[4];
        #pragma unroll
        for (int ni = 0; ni < 4; ++ni)
            bbase[ni] = W1e + (size_t)((nq * 4 + ni) * 32) * 512 + lane * 8;

        f32x4 acc[4][4];
        #pragma unroll
        for (int mi = 0; mi < 4; ++mi)
            #pragma unroll
            for (int ni = 0; ni < 4; ++ni) acc[mi][ni] = (f32x4){0.f,0.f,0.f,0.f};

        bf16x8 ac[4], bc[4];
        #pragma unroll
        for (int mi = 0; mi < 4; ++mi) ac[mi] = *(const bf16x8*)abase[mi];
        #pragma unroll
        for (int ni = 0; ni < 4; ++ni) bc[ni] = *(const bf16x8*)bbase[ni];

        #pragma unroll
        for (int k32 = 0; k32 < 32; ++k32) {
            bf16x8 an[4], bn[4];
            if (k32 < 31) {
                #pragma unroll
                for (int ni = 0; ni < 4; ++ni)
                    bn[ni] = *(const bf16x8*)(bbase[ni] + (size_t)(k32 + 1) * 512);
                #pragma unroll
                for (int mi = 0; mi < 4; ++mi)
                    an[mi] = *(const bf16x8*)(abase[mi] + (k32 + 1) * 32);
            }
            #pragma unroll
            for (int ni = 0; ni < 4; ++ni)
                #pragma unroll
                for (int mi = 0; mi < 4; ++mi)
                    acc[mi][ni] = __builtin_amdgcn_mfma_f32_16x16x32_bf16(ac[mi], bc[ni], acc[mi][ni], 0, 0, 0);
            if (k32 < 31) {
                #pragma unroll
                for (int ni = 0; ni < 4; ++ni) bc[ni] = bn[ni];
                #pragma unroll
                for (int mi = 0; mi < 4; ++mi) ac[mi] = an[mi];
            }
        }

        // h = bf16(C1 + b1) -> swizzled LDS [128 rows][256 cols]
        #pragma unroll
        for (int ni = 0; ni < 4; ++ni) {
            const int n = nq * 64 + ni * 16 + l16;
            const float bv = b1[n];
            #pragma unroll
            for (int mi = 0; mi < 4; ++mi) {
                #pragma unroll
                for (int r = 0; r < 4; ++r) {
                    const int m = mh * 64 + mi * 16 + lk * 4 + r;
                    const int byte = (m * (HDIM * 2) + n * 2) ^ ((m & 7) << 4);
                    *(ushort*)((char*)hlds + byte) = f2b(acc[mi][ni][r] + bv);
                }
            }
        }
    }
    __syncthreads();

    // ---- phase 2: C2[128,1024] = h @ W2, 4 jc chunks x 8 k-steps ----
    {
        for (int jc = 0; jc < 4; ++jc) {
            f32x4 acc2[4][4];
            #pragma unroll
            for (int mi = 0; mi < 4; ++mi)
                #pragma unroll
                for (int ni = 0; ni < 4; ++ni) acc2[mi][ni] = (f32x4){0.f,0.f,0.f,0.f};

            const ushort* b2base[4];
            #pragma unroll
            for (int ni = 0; ni < 4; ++ni)
                b2base[ni] = W2e + (size_t)((jc * 16 + nq * 4 + ni) * 8) * 512 + lane * 8;

            bf16x8 bc2[4];
            #pragma unroll
            for (int ni = 0; ni < 4; ++ni) bc2[ni] = *(const bf16x8*)b2base[ni];

            #pragma unroll
            for (int k32 = 0; k32 < 8; ++k32) {
                bf16x8 a2[4];
                #pragma unroll
                for (int mi = 0; mi < 4; ++mi) {
                    const int m = mh * 64 + mi * 16 + l16;
                    const int byte = (m * (HDIM * 2) + (k32 * 32 + lk * 8) * 2) ^ ((m & 7) << 4);
                    a2[mi] = *(const bf16x8*)((const char*)hlds + byte);
                }
                bf16x8 bn2[4];
                if (k32 < 7) {
                    #pragma unroll
                    for (int ni = 0; ni < 4; ++ni)
                        bn2[ni] = *(const bf16x8*)(b2base[ni] + (size_t)(k32 + 1) * 512);
                }
                #pragma unroll
                for (int ni = 0; ni < 4; ++ni)
                    #pragma unroll
                    for (int mi = 0; mi < 4; ++mi)
                        acc2[mi][ni] = __builtin_amdgcn_mfma_f32_16x16x32_bf16(a2[mi], bc2[ni], acc2[mi][ni], 0, 0, 0);
                if (k32 < 7) {
                    #pragma unroll
                    for (int ni = 0; ni < 4; ++ni) bc2[ni] = bn2[ni];
                }
            }

            if (ATOMIC) {
                #pragma unroll
                for (int ni = 0; ni < 4; ++ni) {
                    const int n = jc * 256 + nq * 64 + ni * 16 + l16;
                    const float bv = b2[n];
                    #pragma unroll
                    for (int mi = 0; mi < 4; ++mi)
                        #pragma unroll
                        for (int r = 0; r < 4; ++r) {
                            const int m = mi * 16 + lk * 4 + r;
                            const float val = gelu_tanh(acc2[mi][ni][r] + bv) * tscs[mh * 64 + m];
                            atomicAdd(&y[(size_t)orow[mh * 64 + m] * DIM + n], val);
                        }
                }
            } else {
                ushort* os = ostage + w * (64 * OSW);
                #pragma unroll
                for (int p = 0; p < 2; ++p) {
                    asm volatile("s_waitcnt lgkmcnt(0)" ::: "memory");
                    #pragma unroll
                    for (int q = 0; q < 2; ++q) {
                        const int ni = p * 2 + q;
                        const float bv = b2[jc * 256 + nq * 64 + ni * 16 + l16];
                        #pragma unroll
                        for (int mi = 0; mi < 4; ++mi)
                            #pragma unroll
                            for (int r = 0; r < 4; ++r) {
                                const int m = mi * 16 + lk * 4 + r;
                                os[m * OSW + q * 16 + l16] = f2b(acc2[mi][ni][r] + bv);
                            }
                    }
                    asm volatile("s_waitcnt lgkmcnt(0)" ::: "memory");
                    #pragma unroll
                    for (int rr = 0; rr < 4; ++rr) {
                        const int m  = rr * 16 + (lane >> 2);
                        const int nl = (lane & 3) * 8;
                        u16x8 vv = *(const u16x8*)(os + m * OSW + nl);
                        *(u16x8*)(sbuf + (size_t)orow[mh * 64 + m] * DIM
                                  + jc * 256 + nq * 64 + p * 32 + nl) = vv;
                    }
                }
            }
        }
    }
}

// ---------------- gather: y = bf16(xn) + sum_s gelu(slot)*score ----------------
__global__ __launch_bounds__(256) void gather_kernel(
    const ushort* __restrict__ sbuf, const float* __restrict__ sscore,
    const ushort* __restrict__ xnb, float* __restrict__ y)
{
    const int idx = blockIdx.x * 256 + threadIdx.x;
    const int t = idx >> 8;
    const int d = (idx & 255) * 4;
    const ushort4 xr = *(const ushort4*)(xnb + (size_t)t * DIM + d);
    float4 a;
    a.x = b2f(xr.x); a.y = b2f(xr.y); a.z = b2f(xr.z); a.w = b2f(xr.w);
    #pragma unroll
    for (int s = 0; s < NSLOT; ++s) {
        const float sc = sscore[(size_t)t * NSLOT + s];
        const ushort4 u = *(const ushort4*)(sbuf + ((size_t)t * NSLOT + s) * DIM + d);
        a.x += gelu_tanh(b2f(u.x)) * sc;
        a.y += gelu_tanh(b2f(u.y)) * sc;
        a.z += gelu_tanh(b2f(u.z)) * sc;
        a.w += gelu_tanh(b2f(u.w)) * sc;
    }
    ((float4*)y)[idx] = a;
}

extern "C" void kernel_launch(void* const* d_in, const int* in_sizes, int n_in,
                              void* d_out, int out_size, void* d_ws, size_t ws_size,
                              hipStream_t stream) {
    const float* x      = (const float*)d_in[0];
    const float* rms_w  = (const float*)d_in[1];
    const float* cent   = (const float*)d_in[2];
    const float* sW1    = (const float*)d_in[3];
    const float* sb1    = (const float*)d_in[4];
    const float* sW2    = (const float*)d_in[5];
    const float* sb2    = (const float*)d_in[6];
    const float* rW1    = (const float*)d_in[7];
    const float* rb1    = (const float*)d_in[8];
    const float* rW2    = (const float*)d_in[9];
    const float* rb2    = (const float*)d_in[10];

    float* y_out   = (float*)d_out;
    float* aff_out = (float*)d_out + (size_t)T_TOK * DIM;

    char* p = (char*)d_ws;
    size_t off = 0;
    auto take = [&](size_t b) {
        char* r = p + off;
        off += (b + 255) & ~(size_t)255;
        return r;
    };
    ushort* xnb    = (ushort*)take((size_t)T_TOK * DIM * 2);
    ushort* W1p    = (ushort*)take((size_t)N_E * DIM * HDIM * 2);
    ushort* W2p    = (ushort*)take((size_t)N_E * HDIM * DIM * 2);
    int*    counts = (int*)take(N_RT * sizeof(int));
    int*    lists  = (int*)take((size_t)N_RT * T_TOK * 4);
    float*  sscore = (float*)take((size_t)T_TOK * NSLOT * 4);
    int*    tk_e   = (int*)take((size_t)T_TOK * TOPK * 4);
    ushort* sbuf   = (ushort*)take(((size_t)T_TOK * NSLOT + TB) * DIM * 2);
    const bool slot_ok = (off <= ws_size);

    pack_weights<DIM, HDIM><<<dim3(64, N_E), dim3(256), 0, stream>>>(sW1, rW1, W1p);
    pack_weights<HDIM, DIM><<<dim3(64, N_E), dim3(256), 0, stream>>>(sW2, rW2, W2p);

    rms_router_kernel<<<dim3(T_TOK / 4), dim3(256), 0, stream>>>(
        x, rms_w, cent, xnb, aff_out, tk_e, sscore);

    scatter_kernel<<<dim3(N_RT), dim3(64), 0, stream>>>(tk_e, counts, lists);

    const int grid = 64 + 8 * MAXPB;
    if (slot_ok) {
        moe_mfma<false><<<dim3(grid), dim3(512), 0, stream>>>(
            xnb, W1p, W2p, sb1, sb2, rb1, rb2, counts, lists,
            sscore, sbuf, y_out);
        gather_kernel<<<dim3((T_TOK * DIM / 4) / 256), dim3(256), 0, stream>>>(
            sbuf, sscore, xnb, y_out);
    } else {
        residual_init<<<dim3((T_TOK * DIM / 4) / 256), dim3(256), 0, stream>>>(
            xnb, y_out);
        moe_mfma<true><<<dim3(grid), dim3(512), 0, stream>>>(
            xnb, W1p, W2p, sb1, sb2, rb1, rb2, counts, lists,
            sscore, sbuf, y_out);
    }
}

// Round 18
// 142.814 us; speedup vs baseline: 1.7012x; 1.1033x over previous
//
#include <hip/hip_runtime.h>
#include <hip/hip_bf16.h>
#include <math.h>

#define T_TOK 4096
#define DIM   1024
#define HDIM  256
#define N_SH  2
#define N_RT  32
#define N_E   34
#define TOPK  4
#define TB    128
#define MAXPB 200
#define NSLOT 6
#define OSW   34          // ostage row stride (32 cols + 2 pad)

typedef short bf16x8 __attribute__((ext_vector_type(8)));
typedef float f32x4  __attribute__((ext_vector_type(4)));
typedef unsigned short u16x8 __attribute__((ext_vector_type(8)));

__device__ __forceinline__ ushort f2b(float v) {
    __hip_bfloat16 h = __float2bfloat16(v);
    return *reinterpret_cast<const ushort*>(&h);
}
__device__ __forceinline__ float b2f(ushort u) {
    unsigned int x = ((unsigned int)u) << 16;
    return __uint_as_float(x);
}
__device__ __forceinline__ float gelu_tanh(float x) {
    float z = 0.7978845608028654f * (x + 0.044715f * x * x * x);
    float e = __expf(2.0f * z);
    float t = 1.0f - 2.0f / (e + 1.0f);
    return 0.5f * x * (1.0f + t);
}

// async global->LDS, 16B per lane; LDS dst wave-uniform base (+lane*16 by HW)
__device__ __forceinline__ void gload_lds16(const ushort* g, ushort* l) {
    __builtin_amdgcn_global_load_lds(
        (const __attribute__((address_space(1))) void*)g,
        (__attribute__((address_space(3))) void*)l,
        16, 0, 0);
}

// ---- pack weights v2: coalesced LDS-transpose (r16-verified) ----
template<int K, int N>
__global__ __launch_bounds__(256) void pack_weights(
    const float* __restrict__ srcS, const float* __restrict__ srcR,
    ushort* __restrict__ dst)
{
    const int e = blockIdx.y;
    const float* src = (e < N_SH) ? (srcS + (size_t)e * K * N)
                                  : (srcR + (size_t)(e - N_SH) * K * N);
    const int kt  = K / 32;
    const int k32 = blockIdx.x % kt;
    const int nc  = blockIdx.x / kt;
    const int tid = threadIdx.x;

    __shared__ ushort ls[32][137];

    #pragma unroll
    for (int it = 0; it < 4; ++it) {
        const int row = it * 8 + (tid >> 5);
        const int c4  = tid & 31;
        const float4 v = *(const float4*)(src + (size_t)(k32 * 32 + row) * N
                                          + nc * 128 + c4 * 4);
        ls[row][c4 * 4 + 0] = f2b(v.x);
        ls[row][c4 * 4 + 1] = f2b(v.y);
        ls[row][c4 * 4 + 2] = f2b(v.z);
        ls[row][c4 * 4 + 3] = f2b(v.w);
    }
    __syncthreads();

    #pragma unroll
    for (int it = 0; it < 2; ++it) {
        const int t8   = tid >> 5;
        const int lane = it * 32 + (tid & 31);
        const int l16 = lane & 15, lk = lane >> 4;
        u16x8 o;
        #pragma unroll
        for (int j = 0; j < 8; ++j)
            o[j] = ls[lk * 8 + j][t8 * 16 + l16];
        const size_t tile = (size_t)(nc * 8 + t8) * kt + k32;
        *(u16x8*)(dst + (size_t)e * K * N + tile * 512 + lane * 8) = o;
    }
}

// ---------------- RMSNorm + router, 4 tokens per block ----------------
__global__ __launch_bounds__(256) void rms_router_kernel(
    const float* __restrict__ x, const float* __restrict__ rms_w,
    const float* __restrict__ cent,
    ushort* __restrict__ xnb, float* __restrict__ aff_out,
    int* __restrict__ tk_e, float* __restrict__ sscore)
{
    const int t0  = blockIdx.x * 4;
    const int tid = threadIdx.x;
    const int wid = tid >> 6;
    const int lane = tid & 63;
    const int t = t0 + wid;

    __shared__ float xsh[4][DIM];
    __shared__ float logits[4][N_RT];

    float4 xv[4], wv[4];
    float ss = 0.f;
    #pragma unroll
    for (int q = 0; q < 4; ++q) {
        xv[q] = ((const float4*)(x + (size_t)t * DIM))[lane + 64 * q];
        ss += xv[q].x*xv[q].x + xv[q].y*xv[q].y + xv[q].z*xv[q].z + xv[q].w*xv[q].w;
    }
    #pragma unroll
    for (int o = 32; o > 0; o >>= 1) ss += __shfl_down(ss, o);
    const float rstd = rsqrtf(__shfl(ss, 0) * (1.0f / (float)DIM) + 1e-6f);

    #pragma unroll
    for (int q = 0; q < 4; ++q)
        wv[q] = ((const float4*)rms_w)[lane + 64 * q];

    #pragma unroll
    for (int q = 0; q < 4; ++q) {
        float4 nv;
        nv.x = xv[q].x * rstd * wv[q].x;
        nv.y = xv[q].y * rstd * wv[q].y;
        nv.z = xv[q].z * rstd * wv[q].z;
        nv.w = xv[q].w * rstd * wv[q].w;
        ushort4 xb = make_ushort4(f2b(nv.x), f2b(nv.y), f2b(nv.z), f2b(nv.w));
        ((ushort4*)(xnb + (size_t)t * DIM))[lane + 64 * q] = xb;
        ((float4*)xsh[wid])[lane + 64 * q] = nv;
    }
    __syncthreads();

    #pragma unroll
    for (int ei = 0; ei < 8; ++ei) {
        const int e = wid * 8 + ei;
        const float4* c4 = (const float4*)(cent + (size_t)e * DIM);
        float a0 = 0.f, a1 = 0.f, a2 = 0.f, a3 = 0.f;
        #pragma unroll
        for (int q = 0; q < 4; ++q) {
            const float4 cv = c4[lane + 64 * q];
            const float4 x0 = ((const float4*)xsh[0])[lane + 64 * q];
            const float4 x1 = ((const float4*)xsh[1])[lane + 64 * q];
            const float4 x2 = ((const float4*)xsh[2])[lane + 64 * q];
            const float4 x3 = ((const float4*)xsh[3])[lane + 64 * q];
            a0 += cv.x*x0.x + cv.y*x0.y + cv.z*x0.z + cv.w*x0.w;
            a1 += cv.x*x1.x + cv.y*x1.y + cv.z*x1.z + cv.w*x1.w;
            a2 += cv.x*x2.x + cv.y*x2.y + cv.z*x2.z + cv.w*x2.w;
            a3 += cv.x*x3.x + cv.y*x3.y + cv.z*x3.z + cv.w*x3.w;
        }
        #pragma unroll
        for (int o = 32; o > 0; o >>= 1) {
            a0 += __shfl_down(a0, o);
            a1 += __shfl_down(a1, o);
            a2 += __shfl_down(a2, o);
            a3 += __shfl_down(a3, o);
        }
        if (lane == 0) {
            logits[0][e] = a0; logits[1][e] = a1;
            logits[2][e] = a2; logits[3][e] = a3;
        }
    }
    __syncthreads();

    {
        float v = (lane < N_RT) ? logits[wid][lane] : -INFINITY;
        float m = v;
        #pragma unroll
        for (int o = 32; o > 0; o >>= 1) m = fmaxf(m, __shfl_xor(m, o));
        float p = (lane < N_RT) ? expf(v - m) : 0.f;
        float s = p;
        #pragma unroll
        for (int o = 32; o > 0; o >>= 1) s += __shfl_xor(s, o);
        const float a = p / s;
        if (lane < N_RT) aff_out[(size_t)t * N_RT + lane] = a;
        if (lane < N_SH) sscore[(size_t)t * NSLOT + lane] = 1.f;

        float vv = (lane < N_RT) ? a : -1.f;
        #pragma unroll
        for (int it = 0; it < TOPK; ++it) {
            float mx = vv;
            #pragma unroll
            for (int o = 32; o > 0; o >>= 1) mx = fmaxf(mx, __shfl_xor(mx, o));
            unsigned long long msk = __ballot(vv == mx);
            int sel = __ffsll((long long)msk) - 1;
            sel = (sel < 0) ? 0 : (sel & (N_RT - 1));
            if (lane == 0) {
                tk_e[(size_t)t * TOPK + it] = sel;
                sscore[(size_t)t * NSLOT + 2 + it] = mx;
            }
            if (lane == sel) vv = -1.f;
        }
    }
}

// ---- scatter: block e compacts (token,slot) entries where tk_e == e ----
__global__ __launch_bounds__(64) void scatter_kernel(
    const int* __restrict__ tk_e, int* __restrict__ counts, int* __restrict__ lists)
{
    const int e    = blockIdx.x;
    const int lane = threadIdx.x;
    const unsigned long long lt = (1ull << lane) - 1ull;
    int base = 0;
    int* lst = lists + (size_t)e * T_TOK;
    for (int c = 0; c < T_TOK * TOPK; c += 256) {
        const int4 v = *(const int4*)(tk_e + c + lane * 4);
        const bool p0 = (v.x == e), p1 = (v.y == e), p2 = (v.z == e), p3 = (v.w == e);
        const unsigned long long m0 = __ballot(p0);
        const unsigned long long m1 = __ballot(p1);
        const unsigned long long m2 = __ballot(p2);
        const unsigned long long m3 = __ballot(p3);
        const int c0 = __popcll(m0), c1 = __popcll(m1), c2 = __popcll(m2);
        if (p0) lst[base + __popcll(m0 & lt)] = c + lane * 4 + 0;
        if (p1) lst[base + c0 + __popcll(m1 & lt)] = c + lane * 4 + 1;
        if (p2) lst[base + c0 + c1 + __popcll(m2 & lt)] = c + lane * 4 + 2;
        if (p3) lst[base + c0 + c1 + c2 + __popcll(m3 & lt)] = c + lane * 4 + 3;
        base += c0 + c1 + c2 + __popcll(m3);
    }
    if (lane == 0) counts[e] = base;
}

// ---- residual init (fallback path only): y = bf16(xn) ----
__global__ __launch_bounds__(256) void residual_init(
    const ushort* __restrict__ xnb, float* __restrict__ y)
{
    const int idx = blockIdx.x * 256 + threadIdx.x;
    const ushort4 xr = *(const ushort4*)(xnb + (size_t)idx * 4);
    float4 a;
    a.x = b2f(xr.x); a.y = b2f(xr.y); a.z = b2f(xr.z); a.w = b2f(xr.w);
    ((float4*)y)[idx] = a;
}

// ---------------- fused 2-layer expert MLP ----------------
// Phase 1 (K=1024): wave (mh=w>>2, nq=w&3): M=64, N=64, 16 MFMA/step.
//   A (4x wave-duplicated operand) staged via global_load_lds, dbuf 8KB/step,
//   one __syncthreads per step (barrier vmcnt-drain makes it race-free).
// Phase 2 (K=256): unchanged (A from hlds), 4 jc chunks x 8 k-steps.
template<bool ATOMIC>
__global__ __launch_bounds__(512, 2) void moe_mfma(
    const ushort* __restrict__ xnb,
    const ushort* __restrict__ W1p, const ushort* __restrict__ W2p,
    const float* __restrict__ sb1, const float* __restrict__ sb2,
    const float* __restrict__ rb1, const float* __restrict__ rb2,
    const int* __restrict__ counts, const int* __restrict__ lists,
    const float* __restrict__ sscore,
    ushort* __restrict__ sbuf, float* __restrict__ y)
{
    const int bi  = blockIdx.x;
    const int tid = threadIdx.x;

    __shared__ int    toks[TB];
    __shared__ int    orow[TB];
    __shared__ float  tscs[TB];
    __shared__ ushort hlds[TB * HDIM];          // 64 KB, XOR-swizzled, stride 512B
    __shared__ ushort astage[2 * 4096];         // 16 KB: [buf][128 tok x 32 dims]
    __shared__ ushort ostage[8 * 64 * OSW];     // 34.8 KB per-wave repack

    int e_full;
    const float *b1, *b2;

    if (bi < 64) {                            // shared experts: 32 tiles x 2
        e_full = bi >> 5;
        const int tile = bi & 31;
        if (tid < TB) {
            const int t = tile * TB + tid;
            toks[tid] = t;
            orow[tid] = ATOMIC ? t : t * NSLOT + e_full;
            tscs[tid] = 1.f;
        }
        b1 = sb1 + e_full * HDIM;  b2 = sb2 + e_full * DIM;
    } else {                                  // routed: bucket walk over counts
        const int j = bi - 64;
        const int b = j & 7, pos = j >> 3;
        int e = -1, tile = 0, accum = 0;
        #pragma unroll
        for (int g = 0; g < 4; ++g) {
            const int eg = b + 8 * g;
            const int tg = (counts[eg] + TB - 1) / TB;
            if (e < 0 && pos < accum + tg) { e = eg; tile = pos - accum; }
            accum += tg;
        }
        if (e < 0) return;
        e_full = N_SH + e;
        const int cnt = counts[e];
        if (tid < TB) {
            const int idx = tile * TB + tid;
            if (idx < cnt) {
                const int lv = lists[(size_t)e * T_TOK + idx];
                const int t = (lv >> 2) & (T_TOK - 1);
                toks[tid] = t;
                orow[tid] = ATOMIC ? t : t * NSLOT + 2 + (lv & 3);
                tscs[tid] = ATOMIC ? sscore[(size_t)t * NSLOT + 2 + (lv & 3)] : 0.f;
            } else {
                toks[tid] = 0;
                orow[tid] = ATOMIC ? 0 : T_TOK * NSLOT;   // dummy row
                tscs[tid] = 0.f;
            }
        }
        b1 = rb1 + e * HDIM;  b2 = rb2 + e * DIM;
    }
    __syncthreads();

    const int w = tid >> 6, lane = tid & 63;
    const int l16 = lane & 15, lk = lane >> 4;
    const int mh = w >> 2;          // token half (64 rows)
    const int nq = w & 3;           // N quarter (64 cols)

    const ushort* W1e = W1p + (size_t)e_full * DIM * HDIM;
    const ushort* W2e = W2p + (size_t)e_full * HDIM * DIM;

    // ---- phase 1: C1[128,256] = X @ W1, wave tile M64 x N64, A via LDS ----
    {
        // per-lane A source: wave w stages tokens w*16..w*16+15 (16 tok x 64B = 1KB)
        const ushort* asrc = xnb + (size_t)toks[w * 16 + (lane >> 2)] * DIM
                             + (lane & 3) * 8;
        // stage k=0 into buf0
        gload_lds16(asrc, astage + w * 512);

        const ushort* bbase[4];
        #pragma unroll
        for (int ni = 0; ni < 4; ++ni)
            bbase[ni] = W1e + (size_t)((nq * 4 + ni) * 32) * 512 + lane * 8;

        f32x4 acc[4][4];
        #pragma unroll
        for (int mi = 0; mi < 4; ++mi)
            #pragma unroll
            for (int ni = 0; ni < 4; ++ni) acc[mi][ni] = (f32x4){0.f,0.f,0.f,0.f};

        bf16x8 bc[4];
        #pragma unroll
        for (int ni = 0; ni < 4; ++ni) bc[ni] = *(const bf16x8*)bbase[ni];
        __syncthreads();                      // stage(0) + toks drained

        #pragma unroll 2
        for (int k32 = 0; k32 < 32; ++k32) {
            const int cur = k32 & 1;
            bf16x8 bn[4];
            if (k32 < 31) {
                gload_lds16(asrc + (k32 + 1) * 32,
                            astage + (cur ^ 1) * 4096 + w * 512);
                #pragma unroll
                for (int ni = 0; ni < 4; ++ni)
                    bn[ni] = *(const bf16x8*)(bbase[ni] + (size_t)(k32 + 1) * 512);
            }
            bf16x8 a[4];
            #pragma unroll
            for (int mi = 0; mi < 4; ++mi) {
                const int tloc = mh * 64 + mi * 16 + l16;
                a[mi] = *(const bf16x8*)(astage + cur * 4096 + tloc * 32 + lk * 8);
            }
            #pragma unroll
            for (int ni = 0; ni < 4; ++ni)
                #pragma unroll
                for (int mi = 0; mi < 4; ++mi)
                    acc[mi][ni] = __builtin_amdgcn_mfma_f32_16x16x32_bf16(a[mi], bc[ni], acc[mi][ni], 0, 0, 0);
            if (k32 < 31) {
                #pragma unroll
                for (int ni = 0; ni < 4; ++ni) bc[ni] = bn[ni];
            }
            __syncthreads();                  // drains DMA(k+1); buf swap safe
        }

        // h = bf16(C1 + b1) -> swizzled LDS [128 rows][256 cols]
        #pragma unroll
        for (int ni = 0; ni < 4; ++ni) {
            const int n = nq * 64 + ni * 16 + l16;
            const float bv = b1[n];
            #pragma unroll
            for (int mi = 0; mi < 4; ++mi) {
                #pragma unroll
                for (int r = 0; r < 4; ++r) {
                    const int m = mh * 64 + mi * 16 + lk * 4 + r;
                    const int byte = (m * (HDIM * 2) + n * 2) ^ ((m & 7) << 4);
                    *(ushort*)((char*)hlds + byte) = f2b(acc[mi][ni][r] + bv);
                }
            }
        }
    }
    __syncthreads();

    // ---- phase 2: C2[128,1024] = h @ W2, 4 jc chunks x 8 k-steps ----
    {
        for (int jc = 0; jc < 4; ++jc) {
            f32x4 acc2[4][4];
            #pragma unroll
            for (int mi = 0; mi < 4; ++mi)
                #pragma unroll
                for (int ni = 0; ni < 4; ++ni) acc2[mi][ni] = (f32x4){0.f,0.f,0.f,0.f};

            const ushort* b2base[4];
            #pragma unroll
            for (int ni = 0; ni < 4; ++ni)
                b2base[ni] = W2e + (size_t)((jc * 16 + nq * 4 + ni) * 8) * 512 + lane * 8;

            bf16x8 bc2[4];
            #pragma unroll
            for (int ni = 0; ni < 4; ++ni) bc2[ni] = *(const bf16x8*)b2base[ni];

            #pragma unroll
            for (int k32 = 0; k32 < 8; ++k32) {
                bf16x8 a2[4];
                #pragma unroll
                for (int mi = 0; mi < 4; ++mi) {
                    const int m = mh * 64 + mi * 16 + l16;
                    const int byte = (m * (HDIM * 2) + (k32 * 32 + lk * 8) * 2) ^ ((m & 7) << 4);
                    a2[mi] = *(const bf16x8*)((const char*)hlds + byte);
                }
                bf16x8 bn2[4];
                if (k32 < 7) {
                    #pragma unroll
                    for (int ni = 0; ni < 4; ++ni)
                        bn2[ni] = *(const bf16x8*)(b2base[ni] + (size_t)(k32 + 1) * 512);
                }
                #pragma unroll
                for (int ni = 0; ni < 4; ++ni)
                    #pragma unroll
                    for (int mi = 0; mi < 4; ++mi)
                        acc2[mi][ni] = __builtin_amdgcn_mfma_f32_16x16x32_bf16(a2[mi], bc2[ni], acc2[mi][ni], 0, 0, 0);
                if (k32 < 7) {
                    #pragma unroll
                    for (int ni = 0; ni < 4; ++ni) bc2[ni] = bn2[ni];
                }
            }

            if (ATOMIC) {
                #pragma unroll
                for (int ni = 0; ni < 4; ++ni) {
                    const int n = jc * 256 + nq * 64 + ni * 16 + l16;
                    const float bv = b2[n];
                    #pragma unroll
                    for (int mi = 0; mi < 4; ++mi)
                        #pragma unroll
                        for (int r = 0; r < 4; ++r) {
                            const int m = mi * 16 + lk * 4 + r;
                            const float val = gelu_tanh(acc2[mi][ni][r] + bv) * tscs[mh * 64 + m];
                            atomicAdd(&y[(size_t)orow[mh * 64 + m] * DIM + n], val);
                        }
                }
            } else {
                ushort* os = ostage + w * (64 * OSW);
                #pragma unroll
                for (int p = 0; p < 2; ++p) {
                    asm volatile("s_waitcnt lgkmcnt(0)" ::: "memory");
                    #pragma unroll
                    for (int q = 0; q < 2; ++q) {
                        const int ni = p * 2 + q;
                        const float bv = b2[jc * 256 + nq * 64 + ni * 16 + l16];
                        #pragma unroll
                        for (int mi = 0; mi < 4; ++mi)
                            #pragma unroll
                            for (int r = 0; r < 4; ++r) {
                                const int m = mi * 16 + lk * 4 + r;
                                os[m * OSW + q * 16 + l16] = f2b(acc2[mi][ni][r] + bv);
                            }
                    }
                    asm volatile("s_waitcnt lgkmcnt(0)" ::: "memory");
                    #pragma unroll
                    for (int rr = 0; rr < 4; ++rr) {
                        const int m  = rr * 16 + (lane >> 2);
                        const int nl = (lane & 3) * 8;
                        u16x8 vv = *(const u16x8*)(os + m * OSW + nl);
                        *(u16x8*)(sbuf + (size_t)orow[mh * 64 + m] * DIM
                                  + jc * 256 + nq * 64 + p * 32 + nl) = vv;
                    }
                }
            }
        }
    }
}

// ---------------- gather: y = bf16(xn) + sum_s gelu(slot)*score ----------------
__global__ __launch_bounds__(256) void gather_kernel(
    const ushort* __restrict__ sbuf, const float* __restrict__ sscore,
    const ushort* __restrict__ xnb, float* __restrict__ y)
{
    const int idx = blockIdx.x * 256 + threadIdx.x;
    const int t = idx >> 8;
    const int d = (idx & 255) * 4;
    const ushort4 xr = *(const ushort4*)(xnb + (size_t)t * DIM + d);
    float4 a;
    a.x = b2f(xr.x); a.y = b2f(xr.y); a.z = b2f(xr.z); a.w = b2f(xr.w);
    #pragma unroll
    for (int s = 0; s < NSLOT; ++s) {
        const float sc = sscore[(size_t)t * NSLOT + s];
        const ushort4 u = *(const ushort4*)(sbuf + ((size_t)t * NSLOT + s) * DIM + d);
        a.x += gelu_tanh(b2f(u.x)) * sc;
        a.y += gelu_tanh(b2f(u.y)) * sc;
        a.z += gelu_tanh(b2f(u.z)) * sc;
        a.w += gelu_tanh(b2f(u.w)) * sc;
    }
    ((float4*)y)[idx] = a;
}

extern "C" void kernel_launch(void* const* d_in, const int* in_sizes, int n_in,
                              void* d_out, int out_size, void* d_ws, size_t ws_size,
                              hipStream_t stream) {
    const float* x      = (const float*)d_in[0];
    const float* rms_w  = (const float*)d_in[1];
    const float* cent   = (const float*)d_in[2];
    const float* sW1    = (const float*)d_in[3];
    const float* sb1    = (const float*)d_in[4];
    const float* sW2    = (const float*)d_in[5];
    const float* sb2    = (const float*)d_in[6];
    const float* rW1    = (const float*)d_in[7];
    const float* rb1    = (const float*)d_in[8];
    const float* rW2    = (const float*)d_in[9];
    const float* rb2    = (const float*)d_in[10];

    float* y_out   = (float*)d_out;
    float* aff_out = (float*)d_out + (size_t)T_TOK * DIM;

    char* p = (char*)d_ws;
    size_t off = 0;
    auto take = [&](size_t b) {
        char* r = p + off;
        off += (b + 255) & ~(size_t)255;
        return r;
    };
    ushort* xnb    = (ushort*)take((size_t)T_TOK * DIM * 2);
    ushort* W1p    = (ushort*)take((size_t)N_E * DIM * HDIM * 2);
    ushort* W2p    = (ushort*)take((size_t)N_E * HDIM * DIM * 2);
    int*    counts = (int*)take(N_RT * sizeof(int));
    int*    lists  = (int*)take((size_t)N_RT * T_TOK * 4);
    float*  sscore = (float*)take((size_t)T_TOK * NSLOT * 4);
    int*    tk_e   = (int*)take((size_t)T_TOK * TOPK * 4);
    ushort* sbuf   = (ushort*)take(((size_t)T_TOK * NSLOT + TB) * DIM * 2);
    const bool slot_ok = (off <= ws_size);

    pack_weights<DIM, HDIM><<<dim3(64, N_E), dim3(256), 0, stream>>>(sW1, rW1, W1p);
    pack_weights<HDIM, DIM><<<dim3(64, N_E), dim3(256), 0, stream>>>(sW2, rW2, W2p);

    rms_router_kernel<<<dim3(T_TOK / 4), dim3(256), 0, stream>>>(
        x, rms_w, cent, xnb, aff_out, tk_e, sscore);

    scatter_kernel<<<dim3(N_RT), dim3(64), 0, stream>>>(tk_e, counts, lists);

    const int grid = 64 + 8 * MAXPB;
    if (slot_ok) {
        moe_mfma<false><<<dim3(grid), dim3(512), 0, stream>>>(
            xnb, W1p, W2p, sb1, sb2, rb1, rb2, counts, lists,
            sscore, sbuf, y_out);
        gather_kernel<<<dim3((T_TOK * DIM / 4) / 256), dim3(256), 0, stream>>>(
            sbuf, sscore, xnb, y_out);
    } else {
        residual_init<<<dim3((T_TOK * DIM / 4) / 256), dim3(256), 0, stream>>>(
            xnb, y_out);
        moe_mfma<true><<<dim3(grid), dim3(512), 0, stream>>>(
            xnb, W1p, W2p, sb1, sb2, rb1, rb2, counts, lists,
            sscore, sbuf, y_out);
    }
}